// Round 1
// 682.487 us; speedup vs baseline: 1.0656x; 1.0656x over previous
//
#include <hip/hip_runtime.h>

#define THREADS 256
#define WAVES_PB 4      // 256 threads = 4 waves
#define ITERS 2         // strided superchunks per wave
// superchunk = 1024 src elems. worst case: 8 * ceil(2048^2/1024) = 32768
// capacity: 4096 blocks * 4 waves * 2 iters = 32768
#define MAX_BLOCKS 4096

// ws layout (uint32):
//  [0..8]   off16 : output prefix, off16[b] = sum_{j<b} 16*s_j^2
//  [9..17]  csum  : superchunk prefix, csum[b] = sum_{j<b} ceil(s_j^2/1024)
//  [18..25] s[b]
//  [26..33] s2[b]
//  [34..41] inv_s[b] (float bits)
__global__ void setup_offsets_kernel(const int* __restrict__ seq,
                                     unsigned int* __restrict__ ws) {
    if (threadIdx.x == 0 && blockIdx.x == 0) {
        unsigned int o16 = 0, cs = 0;
        ws[0] = 0u; ws[9] = 0u;
        for (int b = 0; b < 8; ++b) {
            unsigned int s  = (unsigned int)seq[b];
            unsigned int s2 = s * s;
            o16 += 16u * s2;
            cs  += (s2 + 1023u) >> 10;
            ws[1 + b]  = o16;
            ws[10 + b] = cs;
            ws[18 + b] = s;
            ws[26 + b] = s2;
            ((float*)ws)[34 + b] = 1.0f / (float)s;
        }
    }
}

__global__ void __launch_bounds__(THREADS)
unpad_mask_kernel(const float* __restrict__ mask,     // fp16 promoted to f32 by harness
                  const unsigned int* __restrict__ ws,
                  int* __restrict__ out) {             // bool output as int32
    __shared__ unsigned int off16[9];
    __shared__ unsigned int csum[9];
    __shared__ unsigned int slen[8];
    __shared__ unsigned int ssq[8];
    __shared__ float        sinv[8];

    int tx = threadIdx.x;
    if (tx < 9) { off16[tx] = ws[tx]; csum[tx] = ws[9 + tx]; }
    if (tx < 8) {
        slen[tx] = ws[18 + tx];
        ssq[tx]  = ws[26 + tx];
        sinv[tx] = ((const float*)ws)[34 + tx];
    }
    __syncthreads();

    unsigned int nchunks     = csum[8];
    unsigned int total_waves = gridDim.x * WAVES_PB;
    unsigned int wave_id     = blockIdx.x * WAVES_PB + ((unsigned int)tx >> 6);
    unsigned int lane        = (unsigned int)tx & 63u;

#pragma unroll 1
    for (int it = 0; it < ITERS; ++it) {
        // strided: at any instant all active waves cover CONSECUTIVE chunks
        unsigned int chunk = wave_id + (unsigned int)it * total_waves;
        if (chunk >= nchunks) break;

        // batch search over superchunk prefix (monotone, wave-uniform)
        unsigned int b = 0;
#pragma unroll
        for (int j = 1; j < 8; ++j) b += (chunk >= csum[j]) ? 1u : 0u;

        unsigned int s    = slen[b];
        unsigned int s2   = ssq[b];
        float        inv  = sinv[b];
        unsigned int p0   = (chunk - csum[b]) << 10;   // batch-local, mult of 1024
        unsigned int base = off16[b];
        const float* mb   = mask + ((size_t)b << 22);

        if (s2 - p0 >= 1024u) {
            // ---- fast path: full superchunk (implies s >= 32) ----
            // Phase 1: compute all 4 sub-chunks into registers.
            // 16 independent mask loads in flight -> latency amortized.
            unsigned int q0 = p0 + (lane << 2);
            int4 o[4];
#pragma unroll
            for (int sub = 0; sub < 4; ++sub) {
                unsigned int q   = q0 + ((unsigned int)sub << 8);
                unsigned int row = (unsigned int)((float)q * inv);
                int col = (int)q - (int)(row * s);
                if (col < 0)            { row -= 1u; col += (int)s; }
                else if (col >= (int)s) { row += 1u; col -= (int)s; }

                unsigned int r0 = row;  int c0 = col;
                float v0 = mb[(size_t)r0 * 2048u + (unsigned int)c0];
                c0++; if (c0 == (int)s) { c0 = 0; r0++; }
                float v1 = mb[(size_t)r0 * 2048u + (unsigned int)c0];
                c0++; if (c0 == (int)s) { c0 = 0; r0++; }
                float v2 = mb[(size_t)r0 * 2048u + (unsigned int)c0];
                c0++; if (c0 == (int)s) { c0 = 0; r0++; }
                float v3 = mb[(size_t)r0 * 2048u + (unsigned int)c0];

                o[sub] = make_int4((v0 > 0.5f) ? 1 : 0,
                                   (v1 > 0.5f) ? 1 : 0,
                                   (v2 > 0.5f) ? 1 : 0,
                                   (v3 > 0.5f) ? 1 : 0);
            }

            // Phase 2: per head, write 4KB contiguous (4 x 1KB wave runs).
            if ((s & 1u) == 0u) {
                // even s: every head base is 16B-aligned
                unsigned int off = base + q0;
#pragma unroll
                for (int h = 0; h < 16; ++h) {
                    *(int4*)(out + off)       = o[0];
                    *(int4*)(out + off + 256) = o[1];
                    *(int4*)(out + off + 512) = o[2];
                    *(int4*)(out + off + 768) = o[3];
                    off += s2;
                }
            } else {
                // odd s: alignment class r = h & 3
                unsigned int off = base + q0;
#pragma unroll
                for (int h = 0; h < 16; ++h) {
                    if ((h & 3) == 0) {
                        *(int4*)(out + off)       = o[0];
                        *(int4*)(out + off + 256) = o[1];
                        *(int4*)(out + off + 512) = o[2];
                        *(int4*)(out + off + 768) = o[3];
                    } else if ((h & 3) == 2) {
#pragma unroll
                        for (int sub = 0; sub < 4; ++sub) {
                            unsigned int so = off + ((unsigned int)sub << 8);
                            *(int2*)(out + so)     = make_int2(o[sub].x, o[sub].y);
                            *(int2*)(out + so + 2) = make_int2(o[sub].z, o[sub].w);
                        }
                    } else {
#pragma unroll
                        for (int sub = 0; sub < 4; ++sub) {
                            unsigned int so = off + ((unsigned int)sub << 8);
                            out[so]     = o[sub].x;
                            out[so + 1] = o[sub].y;
                            out[so + 2] = o[sub].z;
                            out[so + 3] = o[sub].w;
                        }
                    }
                    off += s2;
                }
            }
        } else {
            // ---- fallback: partial superchunk tail or tiny s ----
#pragma unroll 1
            for (int sub = 0; sub < 4; ++sub) {
                unsigned int sp0 = p0 + ((unsigned int)sub << 8);
                if (sp0 >= s2) break;

                if (s2 - sp0 >= 256u) {
                    // full 256-chunk (s >= 16): old fast-256 path
                    unsigned int q   = sp0 + (lane << 2);
                    unsigned int row = (unsigned int)((float)q * inv);
                    int col = (int)q - (int)(row * s);
                    if (col < 0)            { row -= 1u; col += (int)s; }
                    else if (col >= (int)s) { row += 1u; col -= (int)s; }

                    unsigned int r0 = row;  int c0 = col;
                    float v0 = mb[(size_t)r0 * 2048u + (unsigned int)c0];
                    c0++; if (c0 == (int)s) { c0 = 0; r0++; }
                    float v1 = mb[(size_t)r0 * 2048u + (unsigned int)c0];
                    c0++; if (c0 == (int)s) { c0 = 0; r0++; }
                    float v2 = mb[(size_t)r0 * 2048u + (unsigned int)c0];
                    c0++; if (c0 == (int)s) { c0 = 0; r0++; }
                    float v3 = mb[(size_t)r0 * 2048u + (unsigned int)c0];

                    int o0 = (v0 > 0.5f) ? 1 : 0;
                    int o1 = (v1 > 0.5f) ? 1 : 0;
                    int o2 = (v2 > 0.5f) ? 1 : 0;
                    int o3 = (v3 > 0.5f) ? 1 : 0;
                    int4 o4  = make_int4(o0, o1, o2, o3);
                    int2 o2a = make_int2(o0, o1);
                    int2 o2b = make_int2(o2, o3);

                    unsigned int off = base + q;
                    if ((s & 1u) == 0u) {
#pragma unroll
                        for (int h = 0; h < 16; ++h) {
                            *(int4*)(out + off) = o4;
                            off += s2;
                        }
                    } else {
#pragma unroll
                        for (int h = 0; h < 16; ++h) {
                            if ((h & 3) == 0) {
                                *(int4*)(out + off) = o4;
                            } else if ((h & 3) == 2) {
                                *(int2*)(out + off)     = o2a;
                                *(int2*)(out + off + 2) = o2b;
                            } else {
                                out[off]     = o0;
                                out[off + 1] = o1;
                                out[off + 2] = o2;
                                out[off + 3] = o3;
                            }
                            off += s2;
                        }
                    }
                } else {
                    // partial tail chunk or tiny s: per-element
#pragma unroll
                    for (int j = 0; j < 4; ++j) {
                        unsigned int p = sp0 + (lane << 2) + (unsigned int)j;
                        if (p >= s2) continue;
                        unsigned int row = (unsigned int)((float)p * inv);
                        int col = (int)p - (int)(row * s);
                        if (col < 0)            { row -= 1u; col += (int)s; }
                        else if (col >= (int)s) { row += 1u; col -= (int)s; }
                        float v = mb[(size_t)row * 2048u + (unsigned int)col];
                        int o = (v > 0.5f) ? 1 : 0;
                        unsigned int off = base + p;
#pragma unroll
                        for (int h = 0; h < 16; ++h) {
                            out[off] = o;
                            off += s2;
                        }
                    }
                }
            }
        }
    }
}

extern "C" void kernel_launch(void* const* d_in, const int* in_sizes, int n_in,
                              void* d_out, int out_size, void* d_ws, size_t ws_size,
                              hipStream_t stream) {
    const float*  mask = (const float*)d_in[0];
    const int*    seq  = (const int*)d_in[1];
    unsigned int* ws   = (unsigned int*)d_ws;   // 42 uints of scratch
    int*          out  = (int*)d_out;

    setup_offsets_kernel<<<1, 64, 0, stream>>>(seq, ws);
    unpad_mask_kernel<<<MAX_BLOCKS, THREADS, 0, stream>>>(mask, ws, out);
}